// Round 2
// baseline (411.823 us; speedup 1.0000x reference)
//
#include <hip/hip_runtime.h>

typedef unsigned short u16;
typedef unsigned int u32;
typedef __attribute__((ext_vector_type(8))) __bf16 bf16x8;
typedef __attribute__((ext_vector_type(4))) float f32x4;
typedef __attribute__((ext_vector_type(8))) unsigned short u16x8;
typedef __attribute__((ext_vector_type(4))) unsigned short u16x4;

#define GLL(gp, lp) __builtin_amdgcn_global_load_lds((const __attribute__((address_space(1))) void*)(gp), (__attribute__((address_space(3))) void*)(lp), 16, 0, 0)

__device__ __forceinline__ u16 f2bf(float f) {
  u32 u = __float_as_uint(f);
  u += 0x7FFFu + ((u >> 16) & 1u);   // RNE; no NaNs in this pipeline
  return (u16)(u >> 16);
}
__device__ __forceinline__ float bf2f(u16 u) { return __uint_as_float(((u32)u) << 16); }
__device__ __forceinline__ float qz(float v) {  // MASE integer_quantizer fwd, width=8 frac=4
  float r = rintf(v * 16.0f);
  r = fminf(127.0f, fmaxf(-128.0f, r));
  return r * 0.0625f;
}
__device__ __forceinline__ f32x4 mfma16(bf16x8 a, bf16x8 b, f32x4 c) {
  return __builtin_amdgcn_mfma_f32_16x16x32_bf16(a, b, c, 0, 0, 0);
}

// ---------------- quantize x, w_qkv, w_out -> bf16 (exact representations) -------------
__global__ __launch_bounds__(256) void k_quant(const float* __restrict__ x,
                                               const float* __restrict__ wqkv,
                                               const float* __restrict__ wout,
                                               u16* __restrict__ xq,
                                               u16* __restrict__ wq,
                                               u16* __restrict__ wo) {
  const int X4 = 4194304;   // 4*8192*512 /4
  const int W4 = 196608;    // 1536*512 /4
  const int O4 = 65536;     // 512*512 /4
  int stride = gridDim.x * blockDim.x;
  for (int i = blockIdx.x * blockDim.x + threadIdx.x; i < X4 + W4 + O4; i += stride) {
    const float4* s; u16* d; int j;
    if (i < X4)            { s = (const float4*)x;    d = xq; j = i; }
    else if (i < X4 + W4)  { s = (const float4*)wqkv; d = wq; j = i - X4; }
    else                   { s = (const float4*)wout; d = wo; j = i - X4 - W4; }
    float4 v = s[j];
    u16x4 o;
    o.x = f2bf(qz(v.x)); o.y = f2bf(qz(v.y)); o.z = f2bf(qz(v.z)); o.w = f2bf(qz(v.w));
    *(u16x4*)(d + (size_t)j * 4) = o;
  }
}

// ---------------- rel_k = positions @ w_rel.T  -> bf16 [8][256][64];  pbR[h][256] ------
// grid (256 rows, 4 col segs), 128 threads. Row 255 is zero padding.
__global__ __launch_bounds__(128) void k_relk(const float* __restrict__ w_rel,
                                              const float* __restrict__ pb,   // [512]
                                              u16* __restrict__ relk,         // [8][256][64]
                                              float* __restrict__ pbR) {      // [8][256]
  int r = blockIdx.x;        // 0..255 (position index; d = r-127)
  int cseg = blockIdx.y;     // 0..3
  int tid = threadIdx.x;     // 0..127
  int c = cseg * 128 + tid;  // output channel 0..511: h = c>>6, d = c&63
  if (r == 255) {            // padding row: zero (read by MFMA B-frags, never selected)
    relk[((size_t)(c >> 6) * 256 + 255) * 64 + (c & 63)] = 0;
    if ((tid & 63) == 0) pbR[(c >> 6) * 256 + 255] = 0.f;
    return;
  }
  __shared__ float pos[512];
  float dd = (float)(r - 127);
  float ad = fabsf(dd);
  float sg = (dd > 0.f) ? 1.f : ((dd < 0.f) ? -1.f : 0.f);
  for (int f = tid; f < 512; f += 128) {
    int base = f & 255;
    float feat;
    if (base < 128) {  // exponential features: half_life = 2^linspace(3, 7, 128)
      float hl = exp2f(3.0f + (float)base * (4.0f / 127.0f));
      feat = expf((-0.6931471805599453f / hl) * ad);
    } else {           // central-mask features: 2^(j+1)-1 > |d|  (2^128 -> inf, matches ref)
      float cw = exp2f((float)(base - 128 + 1)) - 1.0f;
      feat = (cw > ad) ? 1.0f : 0.0f;
    }
    if (f >= 256) feat *= sg;
    pos[f] = feat;
  }
  __syncthreads();
  const float4* wr4 = (const float4*)(w_rel + (size_t)c * 512);
  float acc = 0.f;
  #pragma unroll 4
  for (int f4 = 0; f4 < 128; f4++) {
    float4 w4 = wr4[f4];
    int f = f4 * 4;
    acc += pos[f] * w4.x + pos[f + 1] * w4.y + pos[f + 2] * w4.z + pos[f + 3] * w4.w;
  }
  relk[((size_t)(c >> 6) * 256 + r) * 64 + (c & 63)] = f2bf(acc);
  // pbR[h][r] = sum_d pb[h*64+d] * rel_k_f32[h][r][d]   (wave == one head here)
  float contrib = acc * pb[c];
  #pragma unroll
  for (int off = 1; off < 64; off <<= 1) contrib += __shfl_xor(contrib, off, 64);
  if ((tid & 63) == 0) pbR[(c >> 6) * 256 + r] = contrib;
}

// ---------------- QKV GEMM: [32768,512]bf16 @ [1536,512]bf16^T, scatter to Q/K/V -------
__global__ __launch_bounds__(256) void k_gemm_qkv(const u16* __restrict__ Aq,
                                                  const u16* __restrict__ Bq,
                                                  u16* __restrict__ Qo,
                                                  u16* __restrict__ Ko,
                                                  u16* __restrict__ Vo) {
  __shared__ u16 As[128 * 32];
  __shared__ u16 Bs[128 * 32];
  int tid = threadIdx.x;
  int bid = blockIdx.x;
  int swz = (bid & 7) * (gridDim.x >> 3) + (bid >> 3);   // XCD swizzle (3072 % 8 == 0)
  int m0 = (swz / 12) * 128, n0 = (swz % 12) * 128;
  int wid = tid >> 6, lane = tid & 63, g = lane >> 4, r16 = lane & 15;
  int wm = wid >> 1, wn = wid & 1;
  f32x4 acc[4][4];
  #pragma unroll
  for (int i = 0; i < 4; i++)
    #pragma unroll
    for (int j = 0; j < 4; j++) acc[i][j] = (f32x4){0.f, 0.f, 0.f, 0.f};
  const u16* Ab = Aq + (size_t)m0 * 512;
  const u16* Bb = Bq + (size_t)n0 * 512;
  char* AsB = (char*)As + wid * 1024;
  char* BsB = (char*)Bs + wid * 1024;
  for (int k0 = 0; k0 < 512; k0 += 32) {
    __syncthreads();
    GLL(Ab + (size_t)(tid >> 2) * 512 + k0 + (tid & 3) * 8, AsB);
    GLL(Ab + (size_t)((tid >> 2) + 64) * 512 + k0 + (tid & 3) * 8, AsB + 4096);
    GLL(Bb + (size_t)(tid >> 2) * 512 + k0 + (tid & 3) * 8, BsB);
    GLL(Bb + (size_t)((tid >> 2) + 64) * 512 + k0 + (tid & 3) * 8, BsB + 4096);
    __syncthreads();
    bf16x8 a[4], b[4];
    #pragma unroll
    for (int mt = 0; mt < 4; mt++)
      a[mt] = *(const bf16x8*)(As + (wm * 64 + mt * 16 + r16) * 32 + g * 8);
    #pragma unroll
    for (int nt = 0; nt < 4; nt++)
      b[nt] = *(const bf16x8*)(Bs + (wn * 64 + nt * 16 + r16) * 32 + g * 8);
    #pragma unroll
    for (int mt = 0; mt < 4; mt++)
      #pragma unroll
      for (int nt = 0; nt < 4; nt++) acc[mt][nt] = mfma16(a[mt], b[nt], acc[mt][nt]);
  }
  // scatter epilogue: col -> (h, d, comp); row m -> (b, n);  [b][h][n][64] bf16
  #pragma unroll
  for (int nt = 0; nt < 4; nt++) {
    int col = n0 + wn * 64 + nt * 16 + r16;
    int h = col / 192;
    int rem = col - h * 192;
    int dd = rem / 3;
    int comp = rem - dd * 3;
    u16* dst = (comp == 0) ? Qo : (comp == 1 ? Ko : Vo);
    #pragma unroll
    for (int mt = 0; mt < 4; mt++) {
      int mbase = m0 + wm * 64 + mt * 16 + 4 * g;
      #pragma unroll
      for (int rr = 0; rr < 4; rr++) {
        int m = mbase + rr;
        int bb = m >> 13, nn = m & 8191;
        dst[((size_t)(bb * 8 + h) * 8192 + nn) * 64 + dd] = f2bf(acc[mt][nt][rr]);
      }
    }
  }
}

// ---------------- windowed attention: one block per (b,h,window), 8 waves --------------
__global__ __launch_bounds__(512) void k_attn(const u16* __restrict__ Q,
                                              const u16* __restrict__ K,
                                              const u16* __restrict__ V,
                                              const u16* __restrict__ relk,
                                              const float* __restrict__ pbR,
                                              const float* __restrict__ cb,   // [512]
                                              u16* __restrict__ attout) {
  int bid = blockIdx.x;            // 2048 = 4*8*64
  int bb = bid >> 9;
  int h = (bid >> 6) & 7;
  int w = bid & 63;
  int tid = threadIdx.x;
  int s = tid >> 6;                // wave id == q-stripe (16 rows)
  int lane = tid & 63, g = lane >> 4, r16 = lane & 15;
  const int n0 = w * 128;
  const u16* Qh = Q + ((size_t)(bb * 8 + h) * 8192 + n0) * 64;
  const u16* Kh = K + ((size_t)(bb * 8 + h) * 8192 + n0) * 64;
  const u16* Vh = V + ((size_t)(bb * 8 + h) * 8192 + n0) * 64;
  const u16* Rh = relk + (size_t)h * 256 * 64;
  const float* pbRh = pbR + h * 256;

  __shared__ u16 VT[64 * 128];      // V^T, XOR-swizzled 16B chunks
  __shared__ u16 Pst[8 * 16 * 128]; // per-wave P stripes, XOR-swizzled
  __shared__ float cbK[128];        // content-bias dot key

  // stage V transposed (+swizzle): logical (dv,key) at dv*128 + ((key>>3 ^ (dv&7))<<3) + (key&7)
  {
    int rv = tid >> 2, c0 = (tid & 3) << 4;
    const u16* src = Vh + rv * 64 + c0;
    u16x8 v0 = *(const u16x8*)src;
    u16x8 v1 = *(const u16x8*)(src + 8);
    int chunk = rv >> 3, sub = rv & 7;
    #pragma unroll
    for (int j = 0; j < 8; j++) {
      int dv = c0 + j;
      VT[dv * 128 + ((chunk ^ (dv & 7)) << 3) + sub] = v0[j];
    }
    #pragma unroll
    for (int j = 0; j < 8; j++) {
      int dv = c0 + 8 + j;
      VT[dv * 128 + ((chunk ^ (dv & 7)) << 3) + sub] = v1[j];
    }
  }
  // cbK[k] = sum_d cb[h][d] * K[k][d]   (f32; folds rel_content_bias exactly)
  if (tid < 128) {
    const u16* kr = Kh + tid * 64;
    const float* cbh = cb + h * 64;
    float a = 0.f;
    #pragma unroll 8
    for (int d = 0; d < 64; d++) a += cbh[d] * bf2f(kr[d]);
    cbK[tid] = a;
  }

  // Q fragments (exact bf16, no bias folded in)
  const u16* qptr = Qh + ((s << 4) + r16) * 64 + (g << 3);
  bf16x8 qa0 = *(const bf16x8*)qptr;
  bf16x8 qa1 = *(const bf16x8*)(qptr + 32);

  // content scores: S[q][k] = q . k    (8 col tiles)
  f32x4 sc[8];
  #pragma unroll
  for (int kt = 0; kt < 8; kt++) {
    const u16* kp = Kh + ((kt << 4) + r16) * 64 + (g << 3);
    bf16x8 b0 = *(const bf16x8*)kp;
    bf16x8 b1 = *(const bf16x8*)(kp + 32);
    f32x4 c = {0.f, 0.f, 0.f, 0.f};
    c = mfma16(qa0, b0, c);
    sc[kt] = mfma16(qa1, b1, c);
  }
  // rel logits band: 9 tiles ct = 7-s .. 15-s, + pbR (pos-bias fold)
  f32x4 rl[9];
  #pragma unroll
  for (int t = 0; t < 9; t++) {
    int ct = 7 - s + t;
    const u16* rp = Rh + ((ct << 4) + r16) * 64 + (g << 3);
    bf16x8 b0 = *(const bf16x8*)rp;
    bf16x8 b1 = *(const bf16x8*)(rp + 32);
    f32x4 c = {0.f, 0.f, 0.f, 0.f};
    c = mfma16(qa0, b0, c);
    c = mfma16(qa1, b1, c);
    float pv = pbRh[(ct << 4) + r16];
    c[0] += pv; c[1] += pv; c[2] += pv; c[3] += pv;
    rl[t] = c;
  }
  __syncthreads();   // VT + cbK ready

  // combine: S = (content + cbK)*scale + shift-gather(rel)
  // pos[q][k] = RL[q][127+k-q]; within tile pair: loc = 15 + kk - qq in [0,30]
  #pragma unroll
  for (int kt = 0; kt < 8; kt++) {
    float cbk = cbK[(kt << 4) + r16];
    #pragma unroll
    for (int rr = 0; rr < 4; rr++) {
      int qq = 4 * g + rr;
      int loc = 15 + r16 - qq;
      int srcl = (g << 4) | (loc & 15);
      float vlo = __shfl(rl[kt][rr], srcl, 64);
      float vhi = __shfl(rl[kt + 1][rr], srcl, 64);
      float pos = (loc < 16) ? vlo : vhi;
      sc[kt][rr] = (sc[kt][rr] + cbk) * 0.125f + pos;
    }
  }
  // softmax over k (row-wise; row qq spread across 16 lanes x 8 tiles)
  float inv[4];
  #pragma unroll
  for (int rr = 0; rr < 4; rr++) {
    float m = sc[0][rr];
    #pragma unroll
    for (int kt = 1; kt < 8; kt++) m = fmaxf(m, sc[kt][rr]);
    #pragma unroll
    for (int off = 1; off < 16; off <<= 1) m = fmaxf(m, __shfl_xor(m, off, 64));
    float sum = 0.f;
    #pragma unroll
    for (int kt = 0; kt < 8; kt++) {
      float p = expf(sc[kt][rr] - m);
      sc[kt][rr] = p;
      sum += p;
    }
    #pragma unroll
    for (int off = 1; off < 16; off <<= 1) sum += __shfl_xor(sum, off, 64);
    inv[rr] = 1.0f / sum;
  }
  // write P stripe (bf16, unnormalized; fold 1/sum into epilogue), swizzled
  u16* Pw = Pst + s * (16 * 128);
  #pragma unroll
  for (int kt = 0; kt < 8; kt++) {
    #pragma unroll
    for (int rr = 0; rr < 4; rr++) {
      int qq = 4 * g + rr;
      int k = (kt << 4) + r16;
      Pw[qq * 128 + ((((k >> 3)) ^ (qq & 7)) << 3) + (k & 7)] = f2bf(sc[kt][rr]);
    }
  }
  // PV: out[q][dv] = sum_k P[q][k] V[k][dv]
  f32x4 o[4];
  #pragma unroll
  for (int dvt = 0; dvt < 4; dvt++) o[dvt] = (f32x4){0.f, 0.f, 0.f, 0.f};
  #pragma unroll
  for (int koff = 0; koff < 128; koff += 32) {
    int ach = (koff >> 3) + g;
    bf16x8 a = *(const bf16x8*)(Pw + r16 * 128 + ((ach ^ (r16 & 7)) << 3));
    #pragma unroll
    for (int dvt = 0; dvt < 4; dvt++) {
      int dv = dvt * 16 + r16;
      bf16x8 bv = *(const bf16x8*)(VT + dv * 128 + ((ach ^ (dv & 7)) << 3));
      o[dvt] = mfma16(a, bv, o[dvt]);
    }
  }
  // epilogue -> att[b][n][h*64+dv] bf16
  #pragma unroll
  for (int dvt = 0; dvt < 4; dvt++) {
    #pragma unroll
    for (int rr = 0; rr < 4; rr++) {
      int qq = 4 * g + rr;
      int nrow = n0 + (s << 4) + qq;
      int colo = h * 64 + dvt * 16 + r16;
      attout[((size_t)bb * 8192 + nrow) * 512 + colo] = f2bf(o[dvt][rr] * inv[rr]);
    }
  }
}

// ---------------- output GEMM: [32768,512]bf16 @ [512,512]bf16^T + bias -> f32 ---------
__global__ __launch_bounds__(256) void k_gemm_out(const u16* __restrict__ Aq,
                                                  const u16* __restrict__ Bq,
                                                  const float* __restrict__ bias,
                                                  float* __restrict__ out) {
  __shared__ u16 As[128 * 32];
  __shared__ u16 Bs[128 * 32];
  int tid = threadIdx.x;
  int bid = blockIdx.x;
  int swz = (bid & 7) * (gridDim.x >> 3) + (bid >> 3);   // 1024 % 8 == 0
  int m0 = (swz >> 2) * 128, n0 = (swz & 3) * 128;
  int wid = tid >> 6, lane = tid & 63, g = lane >> 4, r16 = lane & 15;
  int wm = wid >> 1, wn = wid & 1;
  f32x4 acc[4][4];
  #pragma unroll
  for (int i = 0; i < 4; i++)
    #pragma unroll
    for (int j = 0; j < 4; j++) acc[i][j] = (f32x4){0.f, 0.f, 0.f, 0.f};
  const u16* Ab = Aq + (size_t)m0 * 512;
  const u16* Bb = Bq + (size_t)n0 * 512;
  char* AsB = (char*)As + wid * 1024;
  char* BsB = (char*)Bs + wid * 1024;
  for (int k0 = 0; k0 < 512; k0 += 32) {
    __syncthreads();
    GLL(Ab + (size_t)(tid >> 2) * 512 + k0 + (tid & 3) * 8, AsB);
    GLL(Ab + (size_t)((tid >> 2) + 64) * 512 + k0 + (tid & 3) * 8, AsB + 4096);
    GLL(Bb + (size_t)(tid >> 2) * 512 + k0 + (tid & 3) * 8, BsB);
    GLL(Bb + (size_t)((tid >> 2) + 64) * 512 + k0 + (tid & 3) * 8, BsB + 4096);
    __syncthreads();
    bf16x8 a[4], b[4];
    #pragma unroll
    for (int mt = 0; mt < 4; mt++)
      a[mt] = *(const bf16x8*)(As + (wm * 64 + mt * 16 + r16) * 32 + g * 8);
    #pragma unroll
    for (int nt = 0; nt < 4; nt++)
      b[nt] = *(const bf16x8*)(Bs + (wn * 64 + nt * 16 + r16) * 32 + g * 8);
    #pragma unroll
    for (int mt = 0; mt < 4; mt++)
      #pragma unroll
      for (int nt = 0; nt < 4; nt++) acc[mt][nt] = mfma16(a[mt], b[nt], acc[mt][nt]);
  }
  #pragma unroll
  for (int nt = 0; nt < 4; nt++) {
    int col = n0 + wn * 64 + nt * 16 + r16;
    float bv = bias[col];
    #pragma unroll
    for (int mt = 0; mt < 4; mt++) {
      int mbase = m0 + wm * 64 + mt * 16 + 4 * g;
      #pragma unroll
      for (int rr = 0; rr < 4; rr++) {
        int m = mbase + rr;
        out[(size_t)m * 512 + col] = acc[mt][nt][rr] + bv;
      }
    }
  }
}

extern "C" void kernel_launch(void* const* d_in, const int* in_sizes, int n_in,
                              void* d_out, int out_size, void* d_ws, size_t ws_size,
                              hipStream_t stream) {
  const float* x     = (const float*)d_in[0];
  const float* w_qkv = (const float*)d_in[1];
  const float* w_out = (const float*)d_in[2];
  const float* b_out = (const float*)d_in[3];
  const float* w_rel = (const float*)d_in[4];
  const float* cb    = (const float*)d_in[5];   // rel_content_bias [1,8,1,1,64]
  const float* pb    = (const float*)d_in[6];   // rel_pos_bias
  float* out = (float*)d_out;

  char* p = (char*)d_ws;
  u16* xq   = (u16*)p; p += (size_t)32768 * 512 * 2;       // 32 MB
  u16* wq   = (u16*)p; p += (size_t)1536 * 512 * 2;        // 1.5 MB
  u16* wo   = (u16*)p; p += (size_t)512 * 512 * 2;         // 0.5 MB
  u16* relk = (u16*)p; p += (size_t)8 * 256 * 64 * 2;      // 256 KB
  float* pbR = (float*)p; p += (size_t)8 * 256 * 4;        // 8 KB
  u16* Qb   = (u16*)p; p += (size_t)4 * 8 * 8192 * 64 * 2; // 32 MB
  u16* Kb   = (u16*)p; p += (size_t)4 * 8 * 8192 * 64 * 2;
  u16* Vb   = (u16*)p; p += (size_t)4 * 8 * 8192 * 64 * 2;
  u16* att  = (u16*)p; p += (size_t)32768 * 512 * 2;       // 32 MB

  hipLaunchKernelGGL(k_quant, dim3(2048), dim3(256), 0, stream, x, w_qkv, w_out, xq, wq, wo);
  hipLaunchKernelGGL(k_relk, dim3(256, 4), dim3(128), 0, stream, w_rel, pb, relk, pbR);
  hipLaunchKernelGGL(k_gemm_qkv, dim3(3072), dim3(256), 0, stream, xq, wq, Qb, Kb, Vb);
  hipLaunchKernelGGL(k_attn, dim3(2048), dim3(512), 0, stream, Qb, Kb, Vb, relk, pbR, cb, att);
  hipLaunchKernelGGL(k_gemm_out, dim3(1024), dim3(256), 0, stream, att, wo, b_out, out);
}

// Round 3
// 359.502 us; speedup vs baseline: 1.1455x; 1.1455x over previous
//
#include <hip/hip_runtime.h>

typedef unsigned short u16;
typedef unsigned int u32;
typedef __attribute__((ext_vector_type(8))) __bf16 bf16x8;
typedef __attribute__((ext_vector_type(4))) float f32x4;
typedef __attribute__((ext_vector_type(8))) unsigned short u16x8;
typedef __attribute__((ext_vector_type(4))) unsigned short u16x4;

#define GLL(gp, lp) __builtin_amdgcn_global_load_lds((const __attribute__((address_space(1))) void*)(gp), (__attribute__((address_space(3))) void*)(lp), 16, 0, 0)

__device__ __forceinline__ u16 f2bf(float f) {
  u32 u = __float_as_uint(f);
  u += 0x7FFFu + ((u >> 16) & 1u);   // RNE; no NaNs in this pipeline
  return (u16)(u >> 16);
}
__device__ __forceinline__ float bf2f(u16 u) { return __uint_as_float(((u32)u) << 16); }
__device__ __forceinline__ float qz(float v) {  // MASE integer_quantizer fwd, width=8 frac=4
  float r = rintf(v * 16.0f);
  r = fminf(127.0f, fmaxf(-128.0f, r));
  return r * 0.0625f;
}
__device__ __forceinline__ f32x4 mfma16(bf16x8 a, bf16x8 b, f32x4 c) {
  return __builtin_amdgcn_mfma_f32_16x16x32_bf16(a, b, c, 0, 0, 0);
}

// ---------------- quantize x, w_qkv, w_out -> bf16 (exact representations) -------------
// w_qkv rows are PERMUTED on store: src row h*192+d*3+comp -> dst row comp*512+h*64+d,
// so the QKV GEMM's output columns are grouped (comp, h, d) and the epilogue coalesces.
__global__ __launch_bounds__(256) void k_quant(const float* __restrict__ x,
                                               const float* __restrict__ wqkv,
                                               const float* __restrict__ wout,
                                               u16* __restrict__ xq,
                                               u16* __restrict__ wq,
                                               u16* __restrict__ wo) {
  const int X4 = 4194304;   // 4*8192*512 /4
  const int W4 = 196608;    // 1536*512 /4
  const int O4 = 65536;     // 512*512 /4
  int stride = gridDim.x * blockDim.x;
  for (int i = blockIdx.x * blockDim.x + threadIdx.x; i < X4 + W4 + O4; i += stride) {
    const float4* s; u16* d; int jl, jd;
    if (i < X4) {
      s = (const float4*)x; d = xq; jl = i; jd = i;
    } else if (i < X4 + W4) {
      s = (const float4*)wqkv; d = wq;
      jl = i - X4;
      int rs = jl >> 7;            // source row (128 float4 per 512-elem row)
      int jc = jl & 127;
      int h = rs / 192;
      int rem = rs - h * 192;
      int dd = rem / 3;
      int comp = rem - dd * 3;
      jd = (comp * 512 + h * 64 + dd) * 128 + jc;
    } else {
      s = (const float4*)wout; d = wo; jl = i - X4 - W4; jd = jl;
    }
    float4 v = s[jl];
    u16x4 o;
    o.x = f2bf(qz(v.x)); o.y = f2bf(qz(v.y)); o.z = f2bf(qz(v.z)); o.w = f2bf(qz(v.w));
    *(u16x4*)(d + (size_t)jd * 4) = o;
  }
}

// ---------------- rel_k = positions @ w_rel.T  -> bf16 [8][256][64];  pbR[h][256] ------
__global__ __launch_bounds__(128) void k_relk(const float* __restrict__ w_rel,
                                              const float* __restrict__ pb,   // [512]
                                              u16* __restrict__ relk,         // [8][256][64]
                                              float* __restrict__ pbR) {      // [8][256]
  int r = blockIdx.x;        // 0..255 (position index; d = r-127)
  int cseg = blockIdx.y;     // 0..3
  int tid = threadIdx.x;     // 0..127
  int c = cseg * 128 + tid;  // output channel 0..511: h = c>>6, d = c&63
  if (r == 255) {            // padding row: zero (read by MFMA B-frags, never selected)
    relk[((size_t)(c >> 6) * 256 + 255) * 64 + (c & 63)] = 0;
    if ((tid & 63) == 0) pbR[(c >> 6) * 256 + 255] = 0.f;
    return;
  }
  __shared__ float pos[512];
  float dd = (float)(r - 127);
  float ad = fabsf(dd);
  float sg = (dd > 0.f) ? 1.f : ((dd < 0.f) ? -1.f : 0.f);
  for (int f = tid; f < 512; f += 128) {
    int base = f & 255;
    float feat;
    if (base < 128) {  // exponential features: half_life = 2^linspace(3, 7, 128)
      float hl = exp2f(3.0f + (float)base * (4.0f / 127.0f));
      feat = expf((-0.6931471805599453f / hl) * ad);
    } else {           // central-mask features: 2^(j+1)-1 > |d|  (2^128 -> inf, matches ref)
      float cw = exp2f((float)(base - 128 + 1)) - 1.0f;
      feat = (cw > ad) ? 1.0f : 0.0f;
    }
    if (f >= 256) feat *= sg;
    pos[f] = feat;
  }
  __syncthreads();
  const float4* wr4 = (const float4*)(w_rel + (size_t)c * 512);
  float acc = 0.f;
  #pragma unroll 4
  for (int f4 = 0; f4 < 128; f4++) {
    float4 w4 = wr4[f4];
    int f = f4 * 4;
    acc += pos[f] * w4.x + pos[f + 1] * w4.y + pos[f + 2] * w4.z + pos[f + 3] * w4.w;
  }
  relk[((size_t)(c >> 6) * 256 + r) * 64 + (c & 63)] = f2bf(acc);
  float contrib = acc * pb[c];
  #pragma unroll
  for (int off = 1; off < 64; off <<= 1) contrib += __shfl_xor(contrib, off, 64);
  if ((tid & 63) == 0) pbR[(c >> 6) * 256 + r] = contrib;
}

// ---------------- QKV GEMM: [32768,512]bf16 @ [1536,512]bf16^T(permuted rows) ----------
// B rows grouped (comp,h,d) -> epilogue stores are 32B-contiguous runs per 16 lanes.
// LDS tiles XOR-swizzled (chunk ^= (row>>1)&3), pre-swizzled on the GLL source side.
__global__ __launch_bounds__(256) void k_gemm_qkv(const u16* __restrict__ Aq,
                                                  const u16* __restrict__ Bq,
                                                  u16* __restrict__ Qo,
                                                  u16* __restrict__ Ko,
                                                  u16* __restrict__ Vo) {
  __shared__ u16 As[128 * 32];
  __shared__ u16 Bs[128 * 32];
  int tid = threadIdx.x;
  int bid = blockIdx.x;
  int swz = (bid & 7) * (gridDim.x >> 3) + (bid >> 3);   // XCD swizzle (3072 % 8 == 0)
  int m0 = (swz / 12) * 128, n0 = (swz % 12) * 128;
  int wid = tid >> 6, lane = tid & 63, g = lane >> 4, r16 = lane & 15;
  int wm = wid >> 1, wn = wid & 1;
  f32x4 acc[4][4];
  #pragma unroll
  for (int i = 0; i < 4; i++)
    #pragma unroll
    for (int j = 0; j < 4; j++) acc[i][j] = (f32x4){0.f, 0.f, 0.f, 0.f};
  const u16* Ab = Aq + (size_t)m0 * 512;
  const u16* Bb = Bq + (size_t)n0 * 512;
  char* AsB = (char*)As + wid * 1024;
  char* BsB = (char*)Bs + wid * 1024;
  int srow = tid >> 2;
  int scol = ((tid & 3) ^ ((tid >> 3) & 3)) * 8;   // pre-swizzled source chunk
  int gs = (g ^ ((r16 >> 1) & 3)) * 8;             // swizzled read chunk
  for (int k0 = 0; k0 < 512; k0 += 32) {
    __syncthreads();
    GLL(Ab + (size_t)srow * 512 + k0 + scol, AsB);
    GLL(Ab + (size_t)(srow + 64) * 512 + k0 + scol, AsB + 4096);
    GLL(Bb + (size_t)srow * 512 + k0 + scol, BsB);
    GLL(Bb + (size_t)(srow + 64) * 512 + k0 + scol, BsB + 4096);
    __syncthreads();
    bf16x8 a[4], b[4];
    #pragma unroll
    for (int mt = 0; mt < 4; mt++)
      a[mt] = *(const bf16x8*)(As + (wm * 64 + mt * 16 + r16) * 32 + gs);
    #pragma unroll
    for (int nt = 0; nt < 4; nt++)
      b[nt] = *(const bf16x8*)(Bs + (wn * 64 + nt * 16 + r16) * 32 + gs);
    #pragma unroll
    for (int mt = 0; mt < 4; mt++)
      #pragma unroll
      for (int nt = 0; nt < 4; nt++) acc[mt][nt] = mfma16(a[mt], b[nt], acc[mt][nt]);
  }
  // epilogue: col -> (comp | h*64+d); store [b][h][n][64] bf16, 32B-coalesced runs
  #pragma unroll
  for (int nt = 0; nt < 4; nt++) {
    int colc = n0 + wn * 64 + nt * 16 + r16;
    int comp = colc >> 9;
    int hd = colc & 511;
    u16* dst = (comp == 0) ? Qo : (comp == 1 ? Ko : Vo);
    u16* dstp = dst + (size_t)(hd >> 6) * 524288 + (hd & 63);
    #pragma unroll
    for (int mt = 0; mt < 4; mt++) {
      int mbase = m0 + wm * 64 + mt * 16 + 4 * g;
      #pragma unroll
      for (int rr = 0; rr < 4; rr++) {
        int m = mbase + rr;
        int bb = m >> 13, nn = m & 8191;
        dstp[(size_t)bb * 4194304 + (size_t)nn * 64] = f2bf(acc[mt][nt][rr]);
      }
    }
  }
}

// ---------------- windowed attention: one block per (b,h,window), 8 waves --------------
__global__ __launch_bounds__(512) void k_attn(const u16* __restrict__ Q,
                                              const u16* __restrict__ K,
                                              const u16* __restrict__ V,
                                              const u16* __restrict__ relk,
                                              const float* __restrict__ pbR,
                                              const float* __restrict__ cb,   // [512]
                                              u16* __restrict__ attout) {
  int bid = blockIdx.x;            // 2048 = 4*8*64
  int bb = bid >> 9;
  int h = (bid >> 6) & 7;
  int w = bid & 63;
  int tid = threadIdx.x;
  int s = tid >> 6;                // wave id == q-stripe (16 rows)
  int lane = tid & 63, g = lane >> 4, r16 = lane & 15;
  const int n0 = w * 128;
  const u16* Qh = Q + ((size_t)(bb * 8 + h) * 8192 + n0) * 64;
  const u16* Kh = K + ((size_t)(bb * 8 + h) * 8192 + n0) * 64;
  const u16* Vh = V + ((size_t)(bb * 8 + h) * 8192 + n0) * 64;
  const u16* Rh = relk + (size_t)h * 256 * 64;
  const float* pbRh = pbR + h * 256;

  __shared__ u16 VT[64 * 128];      // V^T, XOR-swizzled 16B chunks
  __shared__ u16 Pst[8 * 16 * 128]; // per-wave P stripes, XOR-swizzled
  __shared__ float cbK[128];        // content-bias dot key

  // stage V transposed (+swizzle): logical (dv,key) at dv*128 + ((key>>3 ^ (dv&7))<<3) + (key&7)
  {
    int rv = tid >> 2, c0 = (tid & 3) << 4;
    const u16* src = Vh + rv * 64 + c0;
    u16x8 v0 = *(const u16x8*)src;
    u16x8 v1 = *(const u16x8*)(src + 8);
    int chunk = rv >> 3, sub = rv & 7;
    #pragma unroll
    for (int j = 0; j < 8; j++) {
      int dv = c0 + j;
      VT[dv * 128 + ((chunk ^ (dv & 7)) << 3) + sub] = v0[j];
    }
    #pragma unroll
    for (int j = 0; j < 8; j++) {
      int dv = c0 + 8 + j;
      VT[dv * 128 + ((chunk ^ (dv & 7)) << 3) + sub] = v1[j];
    }
  }
  // cbK[k] = sum_d cb[h][d] * K[k][d]   (f32; folds rel_content_bias exactly)
  if (tid < 128) {
    const u16x8* kr8 = (const u16x8*)(Kh + tid * 64);
    const float* cbh = cb + h * 64;
    float a = 0.f;
    #pragma unroll
    for (int d8 = 0; d8 < 8; d8++) {
      u16x8 kv = kr8[d8];
      #pragma unroll
      for (int j = 0; j < 8; j++) a += cbh[d8 * 8 + j] * bf2f(kv[j]);
    }
    cbK[tid] = a;
  }

  // Q fragments (exact bf16, no bias folded in)
  const u16* qptr = Qh + ((s << 4) + r16) * 64 + (g << 3);
  bf16x8 qa0 = *(const bf16x8*)qptr;
  bf16x8 qa1 = *(const bf16x8*)(qptr + 32);

  // content scores: S[q][k] = q . k    (8 col tiles)
  f32x4 sc[8];
  #pragma unroll
  for (int kt = 0; kt < 8; kt++) {
    const u16* kp = Kh + ((kt << 4) + r16) * 64 + (g << 3);
    bf16x8 b0 = *(const bf16x8*)kp;
    bf16x8 b1 = *(const bf16x8*)(kp + 32);
    f32x4 c = {0.f, 0.f, 0.f, 0.f};
    c = mfma16(qa0, b0, c);
    sc[kt] = mfma16(qa1, b1, c);
  }
  // rel logits band: 9 tiles ct = 7-s .. 15-s, + pbR (pos-bias fold)
  f32x4 rl[9];
  #pragma unroll
  for (int t = 0; t < 9; t++) {
    int ct = 7 - s + t;
    const u16* rp = Rh + ((ct << 4) + r16) * 64 + (g << 3);
    bf16x8 b0 = *(const bf16x8*)rp;
    bf16x8 b1 = *(const bf16x8*)(rp + 32);
    f32x4 c = {0.f, 0.f, 0.f, 0.f};
    c = mfma16(qa0, b0, c);
    c = mfma16(qa1, b1, c);
    float pv = pbRh[(ct << 4) + r16];
    c[0] += pv; c[1] += pv; c[2] += pv; c[3] += pv;
    rl[t] = c;
  }
  __syncthreads();   // VT + cbK ready

  // combine: S = (content + cbK)*scale + shift-gather(rel)
  #pragma unroll
  for (int kt = 0; kt < 8; kt++) {
    float cbk = cbK[(kt << 4) + r16];
    #pragma unroll
    for (int rr = 0; rr < 4; rr++) {
      int qq = 4 * g + rr;
      int loc = 15 + r16 - qq;
      int srcl = (g << 4) | (loc & 15);
      float vlo = __shfl(rl[kt][rr], srcl, 64);
      float vhi = __shfl(rl[kt + 1][rr], srcl, 64);
      float pos = (loc < 16) ? vlo : vhi;
      sc[kt][rr] = (sc[kt][rr] + cbk) * 0.125f + pos;
    }
  }
  // softmax over k (row-wise; row qq spread across 16 lanes x 8 tiles)
  float inv[4];
  #pragma unroll
  for (int rr = 0; rr < 4; rr++) {
    float m = sc[0][rr];
    #pragma unroll
    for (int kt = 1; kt < 8; kt++) m = fmaxf(m, sc[kt][rr]);
    #pragma unroll
    for (int off = 1; off < 16; off <<= 1) m = fmaxf(m, __shfl_xor(m, off, 64));
    float sum = 0.f;
    #pragma unroll
    for (int kt = 0; kt < 8; kt++) {
      float p = expf(sc[kt][rr] - m);
      sc[kt][rr] = p;
      sum += p;
    }
    #pragma unroll
    for (int off = 1; off < 16; off <<= 1) sum += __shfl_xor(sum, off, 64);
    inv[rr] = 1.0f / sum;
  }
  // write P stripe (bf16, unnormalized; fold 1/sum into epilogue), swizzled
  u16* Pw = Pst + s * (16 * 128);
  #pragma unroll
  for (int kt = 0; kt < 8; kt++) {
    #pragma unroll
    for (int rr = 0; rr < 4; rr++) {
      int qq = 4 * g + rr;
      int k = (kt << 4) + r16;
      Pw[qq * 128 + ((((k >> 3)) ^ (qq & 7)) << 3) + (k & 7)] = f2bf(sc[kt][rr]);
    }
  }
  // PV: out[q][dv] = sum_k P[q][k] V[k][dv]
  f32x4 o[4];
  #pragma unroll
  for (int dvt = 0; dvt < 4; dvt++) o[dvt] = (f32x4){0.f, 0.f, 0.f, 0.f};
  #pragma unroll
  for (int koff = 0; koff < 128; koff += 32) {
    int ach = (koff >> 3) + g;
    bf16x8 a = *(const bf16x8*)(Pw + r16 * 128 + ((ach ^ (r16 & 7)) << 3));
    #pragma unroll
    for (int dvt = 0; dvt < 4; dvt++) {
      int dv = dvt * 16 + r16;
      bf16x8 bv = *(const bf16x8*)(VT + dv * 128 + ((ach ^ (dv & 7)) << 3));
      o[dvt] = mfma16(a, bv, o[dvt]);
    }
  }
  // epilogue -> att[b][n][h*64+dv] bf16
  #pragma unroll
  for (int dvt = 0; dvt < 4; dvt++) {
    #pragma unroll
    for (int rr = 0; rr < 4; rr++) {
      int qq = 4 * g + rr;
      int nrow = n0 + (s << 4) + qq;
      int colo = h * 64 + dvt * 16 + r16;
      attout[((size_t)bb * 8192 + nrow) * 512 + colo] = f2bf(o[dvt][rr] * inv[rr]);
    }
  }
}

// ---------------- output GEMM: [32768,512]bf16 @ [512,512]bf16^T + bias -> f32 ---------
__global__ __launch_bounds__(256) void k_gemm_out(const u16* __restrict__ Aq,
                                                  const u16* __restrict__ Bq,
                                                  const float* __restrict__ bias,
                                                  float* __restrict__ out) {
  __shared__ u16 As[128 * 32];
  __shared__ u16 Bs[128 * 32];
  int tid = threadIdx.x;
  int bid = blockIdx.x;
  int swz = (bid & 7) * (gridDim.x >> 3) + (bid >> 3);   // 1024 % 8 == 0
  int m0 = (swz >> 2) * 128, n0 = (swz & 3) * 128;
  int wid = tid >> 6, lane = tid & 63, g = lane >> 4, r16 = lane & 15;
  int wm = wid >> 1, wn = wid & 1;
  f32x4 acc[4][4];
  #pragma unroll
  for (int i = 0; i < 4; i++)
    #pragma unroll
    for (int j = 0; j < 4; j++) acc[i][j] = (f32x4){0.f, 0.f, 0.f, 0.f};
  const u16* Ab = Aq + (size_t)m0 * 512;
  const u16* Bb = Bq + (size_t)n0 * 512;
  char* AsB = (char*)As + wid * 1024;
  char* BsB = (char*)Bs + wid * 1024;
  int srow = tid >> 2;
  int scol = ((tid & 3) ^ ((tid >> 3) & 3)) * 8;
  int gs = (g ^ ((r16 >> 1) & 3)) * 8;
  for (int k0 = 0; k0 < 512; k0 += 32) {
    __syncthreads();
    GLL(Ab + (size_t)srow * 512 + k0 + scol, AsB);
    GLL(Ab + (size_t)(srow + 64) * 512 + k0 + scol, AsB + 4096);
    GLL(Bb + (size_t)srow * 512 + k0 + scol, BsB);
    GLL(Bb + (size_t)(srow + 64) * 512 + k0 + scol, BsB + 4096);
    __syncthreads();
    bf16x8 a[4], b[4];
    #pragma unroll
    for (int mt = 0; mt < 4; mt++)
      a[mt] = *(const bf16x8*)(As + (wm * 64 + mt * 16 + r16) * 32 + gs);
    #pragma unroll
    for (int nt = 0; nt < 4; nt++)
      b[nt] = *(const bf16x8*)(Bs + (wn * 64 + nt * 16 + r16) * 32 + gs);
    #pragma unroll
    for (int mt = 0; mt < 4; mt++)
      #pragma unroll
      for (int nt = 0; nt < 4; nt++) acc[mt][nt] = mfma16(a[mt], b[nt], acc[mt][nt]);
  }
  #pragma unroll
  for (int nt = 0; nt < 4; nt++) {
    int col = n0 + wn * 64 + nt * 16 + r16;
    float bv = bias[col];
    #pragma unroll
    for (int mt = 0; mt < 4; mt++) {
      int mbase = m0 + wm * 64 + mt * 16 + 4 * g;
      #pragma unroll
      for (int rr = 0; rr < 4; rr++) {
        int m = mbase + rr;
        out[(size_t)m * 512 + col] = acc[mt][nt][rr] + bv;
      }
    }
  }
}

extern "C" void kernel_launch(void* const* d_in, const int* in_sizes, int n_in,
                              void* d_out, int out_size, void* d_ws, size_t ws_size,
                              hipStream_t stream) {
  const float* x     = (const float*)d_in[0];
  const float* w_qkv = (const float*)d_in[1];
  const float* w_out = (const float*)d_in[2];
  const float* b_out = (const float*)d_in[3];
  const float* w_rel = (const float*)d_in[4];
  const float* cb    = (const float*)d_in[5];   // rel_content_bias [1,8,1,1,64]
  const float* pb    = (const float*)d_in[6];   // rel_pos_bias
  float* out = (float*)d_out;

  char* p = (char*)d_ws;
  u16* xq   = (u16*)p; p += (size_t)32768 * 512 * 2;       // 32 MB
  u16* wq   = (u16*)p; p += (size_t)1536 * 512 * 2;        // 1.5 MB (rows permuted: comp,h,d)
  u16* wo   = (u16*)p; p += (size_t)512 * 512 * 2;         // 0.5 MB
  u16* relk = (u16*)p; p += (size_t)8 * 256 * 64 * 2;      // 256 KB
  float* pbR = (float*)p; p += (size_t)8 * 256 * 4;        // 8 KB
  u16* Qb   = (u16*)p; p += (size_t)4 * 8 * 8192 * 64 * 2; // 32 MB
  u16* Kb   = (u16*)p; p += (size_t)4 * 8 * 8192 * 64 * 2;
  u16* Vb   = (u16*)p; p += (size_t)4 * 8 * 8192 * 64 * 2;
  u16* att  = (u16*)p; p += (size_t)32768 * 512 * 2;       // 32 MB

  hipLaunchKernelGGL(k_quant, dim3(2048), dim3(256), 0, stream, x, w_qkv, w_out, xq, wq, wo);
  hipLaunchKernelGGL(k_relk, dim3(256, 4), dim3(128), 0, stream, w_rel, pb, relk, pbR);
  hipLaunchKernelGGL(k_gemm_qkv, dim3(3072), dim3(256), 0, stream, xq, wq, Qb, Kb, Vb);
  hipLaunchKernelGGL(k_attn, dim3(2048), dim3(512), 0, stream, Qb, Kb, Vb, relk, pbR, cb, att);
  hipLaunchKernelGGL(k_gemm_out, dim3(1024), dim3(256), 0, stream, att, wo, b_out, out);
}